// Round 8
// baseline (352.538 us; speedup 1.0000x reference)
//
#include <hip/hip_runtime.h>
#include <math.h>

#define NB 256          // batch
#define XW 5048         // input row width
#define GENE 3000
#define DRUGW 2048
#define EPSF 1e-5f

struct Params {
    const float* x;
    const int* cols0; const float* w0; const float* b0;
    const int* cols1; const float* w1; const float* b1;
    const float* w2;  const float* b2;
    const float* gg;  const float* eg;
    const float* g1;  const float* e1;
    const float* g2;  const float* e2;
    const float* Wd1; const float* bd1;
    const float* gd1; const float* ed1;
    const float* Wd2; const float* bd2;
    const float* gd2; const float* ed2;
    const float* Wd3; const float* bd3;
    const float* gd3; const float* ed3;
    const float* gf;  const float* ef;
    const float* Wf;  const float* bf;
    const float* ga;  const float* ea;
    const float* Wa;  const float* ba;
    const float* Wo;  const float* bo;
    float* out;
    float* gene_n; float* drug_n; float* h1n; float* h2n;
    float* fbt;     // 56-feature concat buffer, BATCH-major: fbt[b*56 + f]
    float* d1n; float* d2n;
};

// ---------------------------------------------------------------------------
// BN epilogue: thread b = batch index owns v[NR] for rows r0..r0+NR-1.
// Store normalized at out[k*RS + b*BS].
// ---------------------------------------------------------------------------
template<int NR>
__device__ __forceinline__ void bn_fold(float (&v)[NR], int b,
        const float* __restrict__ g, const float* __restrict__ e,
        float* __restrict__ out, int RS, int BS) {
    __shared__ float sred[NR][4][2];
    __shared__ float s_ac[2][NR];
    int lane = b & 63, wv = b >> 6;
    float s1[NR], s2[NR];
    #pragma unroll
    for (int k = 0; k < NR; k++) { s1[k] = v[k]; s2[k] = v[k] * v[k]; }
    #pragma unroll
    for (int off = 32; off >= 1; off >>= 1) {
        #pragma unroll
        for (int k = 0; k < NR; k++) {
            s1[k] += __shfl_xor(s1[k], off);
            s2[k] += __shfl_xor(s2[k], off);
        }
    }
    if (lane == 0) {
        #pragma unroll
        for (int k = 0; k < NR; k++) { sred[k][wv][0] = s1[k]; sred[k][wv][1] = s2[k]; }
    }
    __syncthreads();
    if (b < NR) {
        float t1 = sred[b][0][0] + sred[b][1][0] + sred[b][2][0] + sred[b][3][0];
        float t2 = sred[b][0][1] + sred[b][1][1] + sred[b][2][1] + sred[b][3][1];
        float mu  = t1 * (1.0f / 256.0f);
        float var = t2 * (1.0f / 256.0f) - mu * mu;
        float rs  = rsqrtf(var + EPSF);
        float aa  = g[b] * rs;
        s_ac[0][b] = aa;
        s_ac[1][b] = e[b] - aa * mu;
    }
    __syncthreads();
    #pragma unroll
    for (int k = 0; k < NR; k++)
        out[k * RS + b * BS] = s_ac[0][k] * v[k] + s_ac[1][k];
}

// ---------------------------------------------------------------------------
// K0: input BN. 32-col tiles, coalesced read of x, LDS transpose, write
// normalized feature-major gene_n / drug_n.
// ---------------------------------------------------------------------------
__global__ void k_inbn(Params p) {
    __shared__ float tile[32 * 257];
    __shared__ float red1[8][33], red2[8][33];
    __shared__ float s_a[32], s_c[32];
    int t = threadIdx.x;
    int tx = t & 31, ty = t >> 5;
    int c0 = blockIdx.x * 32;
    int c = c0 + tx;
    bool valid = c < XW;
    float s1 = 0.f, s2 = 0.f;
    #pragma unroll 8
    for (int i = 0; i < 32; i++) {
        int r = ty * 32 + i;
        float v = valid ? p.x[(size_t)r * XW + c] : 0.f;
        tile[tx * 257 + r] = v;
        s1 += v; s2 += v * v;
    }
    red1[ty][tx] = s1; red2[ty][tx] = s2;
    __syncthreads();
    if (t < 32) {
        float t1 = 0.f, t2 = 0.f;
        #pragma unroll
        for (int k = 0; k < 8; k++) { t1 += red1[k][t]; t2 += red2[k][t]; }
        float mu  = t1 * (1.0f / 256.0f);
        float var = t2 * (1.0f / 256.0f) - mu * mu;
        float rs  = rsqrtf(var + EPSF);
        int col = c0 + t;
        float gv = 0.f, ev = 0.f;
        if (col < GENE)      { gv = p.gg[col];         ev = p.eg[col]; }
        else if (col < XW)   { gv = p.gd1[col - GENE]; ev = p.ed1[col - GENE]; }
        float aa = gv * rs;
        s_a[t] = aa; s_c[t] = ev - aa * mu;
    }
    __syncthreads();
    #pragma unroll 4
    for (int cc = 0; cc < 32; cc++) {
        int col = c0 + cc;
        if (col >= XW) break;
        float w = s_a[cc] * tile[cc * 257 + t] + s_c[cc];
        if (col < GENE) p.gene_n[(size_t)col * NB + t] = w;
        else            p.drug_n[(size_t)(col - GENE) * NB + t] = w;
    }
}

// ---------------------------------------------------------------------------
// K1: splin0 (1500 tasks) || dense1 one-shot (64 tasks x 2 outputs).
// Deep-ILP bodies: batched index loads -> batched gathers -> FMA.
// ---------------------------------------------------------------------------
__global__ void k_s1(Params p) {
    int task = blockIdx.x, b = threadIdx.x;
    if (task < 1500) {
        int t = task;
        int base = t * 180;
        int cc[30];
        #pragma unroll
        for (int i = 0; i < 30; i++) cc[i] = p.cols0[base + i * 6];
        float v[30];
        #pragma unroll
        for (int i = 0; i < 30; i++) v[i] = p.gene_n[(size_t)cc[i] * NB + b];
        float acc[6] = {0.f, 0.f, 0.f, 0.f, 0.f, 0.f};
        #pragma unroll
        for (int i = 0; i < 30; i++)
            #pragma unroll
            for (int k = 0; k < 6; k++) acc[k] += v[i] * p.w0[base + i * 6 + k];
        float v6[6];
        #pragma unroll
        for (int k = 0; k < 6; k++) v6[k] = tanhf(acc[k] + p.b0[t * 6 + k]);
        bn_fold<6>(v6, b, p.g1 + t * 6, p.e1 + t * 6,
                   p.h1n + (size_t)t * 6 * NB, NB, 1);
    } else {
        int j0 = (task - 1500) * 2;              // 2 outputs, 2048 cols
        const float* w0r = p.Wd1 + (size_t)j0 * DRUGW;
        const float* w1r = w0r + DRUGW;
        // 4-way split accumulators per output (FMA chain 2048 -> 512)
        float a0[4] = {0.f,0.f,0.f,0.f}, a1[4] = {0.f,0.f,0.f,0.f};
        for (int c0 = 0; c0 < DRUGW; c0 += 16) {
            float v[16];
            #pragma unroll
            for (int u = 0; u < 16; u++)
                v[u] = p.drug_n[(size_t)(c0 + u) * NB + b];
            #pragma unroll
            for (int u = 0; u < 16; u++) {
                a0[u & 3] += v[u] * w0r[c0 + u];
                a1[u & 3] += v[u] * w1r[c0 + u];
            }
        }
        float v2[2];
        v2[0] = tanhf(a0[0] + a0[1] + a0[2] + a0[3] + p.bd1[j0]);
        v2[1] = tanhf(a1[0] + a1[1] + a1[2] + a1[3] + p.bd1[j0 + 1]);
        bn_fold<2>(v2, b, p.gd2 + j0, p.ed2 + j0,
                   p.d1n + (size_t)j0 * NB, NB, 1);
    }
}

// ---------------------------------------------------------------------------
// K2: splin1 (400 tasks) || dense2 (8 tasks x 8 outputs, 128 cols)
// ---------------------------------------------------------------------------
__global__ void k_s2(Params p) {
    int task = blockIdx.x, b = threadIdx.x;
    if (task < 400) {
        int o = task;
        int cb[5];
        #pragma unroll
        for (int pi = 0; pi < 5; pi++) cb[pi] = p.cols1[(o * 5 + pi) * 36];
        float v[30];
        #pragma unroll
        for (int pi = 0; pi < 5; pi++)
            #pragma unroll
            for (int j = 0; j < 6; j++)
                v[pi * 6 + j] = p.h1n[(size_t)(cb[pi] + j) * NB + b];
        float acc[6] = {0.f, 0.f, 0.f, 0.f, 0.f, 0.f};
        #pragma unroll
        for (int pi = 0; pi < 5; pi++) {
            int qb = (o * 5 + pi) * 36;
            #pragma unroll
            for (int j = 0; j < 6; j++)
                #pragma unroll
                for (int i = 0; i < 6; i++)
                    acc[i] += v[pi * 6 + j] * p.w1[qb + i * 6 + j];
        }
        float v6[6];
        #pragma unroll
        for (int i = 0; i < 6; i++) v6[i] = tanhf(acc[i] + p.b1[o * 6 + i]);
        bn_fold<6>(v6, b, p.g2 + o * 6, p.e2 + o * 6,
                   p.h2n + (size_t)o * 6 * NB, NB, 1);
    } else {
        int j0 = (task - 400) * 8;               // dense2: 128 -> 64
        float acc[8] = {0.f,0.f,0.f,0.f,0.f,0.f,0.f,0.f};
        for (int c0 = 0; c0 < 128; c0 += 16) {
            float v[16];
            #pragma unroll
            for (int u = 0; u < 16; u++)
                v[u] = p.d1n[(size_t)(c0 + u) * NB + b];
            #pragma unroll
            for (int u = 0; u < 16; u++)
                #pragma unroll
                for (int jj = 0; jj < 8; jj++)
                    acc[jj] += v[u] * p.Wd2[(size_t)(j0 + jj) * 128 + c0 + u];
        }
        float v8[8];
        #pragma unroll
        for (int jj = 0; jj < 8; jj++) v8[jj] = tanhf(acc[jj] + p.bd2[j0 + jj]);
        bn_fold<8>(v8, b, p.gd3 + j0, p.ed3 + j0,
                   p.d2n + (size_t)j0 * NB, NB, 1);
    }
}

// ---------------------------------------------------------------------------
// K3: splin2 one-shot (24 tasks, 8-term rounds = 48 loads in flight,
// per-j accumulators) || dense3 (4 tasks x 8, 64 cols).
// Both store into fbt BATCH-major (fbt[b*56+f]).
// ---------------------------------------------------------------------------
__global__ void k_s3(Params p) {
    int task = blockIdx.x, b = threadIdx.x;
    if (task < 24) {
        int kf = task;
        float acc[6] = {0.f, 0.f, 0.f, 0.f, 0.f, 0.f};   // per-j partials
        for (int t0 = 0; t0 < 400; t0 += 8) {
            float v[48];
            #pragma unroll
            for (int u = 0; u < 8; u++)
                #pragma unroll
                for (int j = 0; j < 6; j++)
                    v[u * 6 + j] = p.h2n[(size_t)((t0 + u) * 6 + j) * NB + b];
            #pragma unroll
            for (int u = 0; u < 8; u++) {
                const float* wt = p.w2 + (t0 + u) * 144 + kf * 6;
                #pragma unroll
                for (int j = 0; j < 6; j++)
                    acc[j] += v[u * 6 + j] * wt[j];
            }
        }
        float s = ((acc[0] + acc[1]) + (acc[2] + acc[3])) + (acc[4] + acc[5]);
        float v1[1] = { tanhf(s + p.b2[kf]) };
        bn_fold<1>(v1, b, p.gf + kf, p.ef + kf, p.fbt + kf, 1, 56);
    } else {
        int j0 = (task - 24) * 8;                // dense3: 64 -> 32
        float acc[8] = {0.f,0.f,0.f,0.f,0.f,0.f,0.f,0.f};
        for (int c0 = 0; c0 < 64; c0 += 16) {
            float v[16];
            #pragma unroll
            for (int u = 0; u < 16; u++)
                v[u] = p.d2n[(size_t)(c0 + u) * NB + b];
            #pragma unroll
            for (int u = 0; u < 16; u++)
                #pragma unroll
                for (int jj = 0; jj < 8; jj++)
                    acc[jj] += v[u] * p.Wd3[(size_t)(j0 + jj) * 64 + c0 + u];
        }
        float v8[8];
        #pragma unroll
        for (int jj = 0; jj < 8; jj++) v8[jj] = tanhf(acc[jj] + p.bd3[j0 + jj]);
        bn_fold<8>(v8, b, p.gf + 24 + j0, p.ef + 24 + j0,
                   p.fbt + 24 + j0, 1, 56);
    }
}

// ---------------------------------------------------------------------------
// K4 (1 block): o1 = tanh(fbt_row @ Wf.T + bf); BN(ga,ea); head.
// ---------------------------------------------------------------------------
__global__ void k_tail(Params p) {
    __shared__ float sred[64][4][2];
    __shared__ float s_ac[2][64];
    int b = threadIdx.x;
    int lane = b & 63, wv = b >> 6;

    float row[56];
    const float4* rp = (const float4*)(p.fbt + (size_t)b * 56);
    #pragma unroll
    for (int i = 0; i < 14; i++) {
        float4 q = rp[i];
        row[i * 4 + 0] = q.x; row[i * 4 + 1] = q.y;
        row[i * 4 + 2] = q.z; row[i * 4 + 3] = q.w;
    }

    float v[64];
    #pragma unroll 4
    for (int j = 0; j < 64; j++) {
        float acc = p.bf[j];
        const float4* wr = (const float4*)(p.Wf + j * 56);   // 224B offset: 16B-aligned
        #pragma unroll
        for (int i = 0; i < 14; i++) {
            float4 q = wr[i];
            acc += row[i*4+0]*q.x + row[i*4+1]*q.y + row[i*4+2]*q.z + row[i*4+3]*q.w;
        }
        v[j] = tanhf(acc);
    }

    #pragma unroll
    for (int k = 0; k < 64; k++) {
        float s1 = v[k], s2 = v[k] * v[k];
        #pragma unroll
        for (int off = 32; off >= 1; off >>= 1) {
            s1 += __shfl_xor(s1, off);
            s2 += __shfl_xor(s2, off);
        }
        if (lane == 0) { sred[k][wv][0] = s1; sred[k][wv][1] = s2; }
    }
    __syncthreads();
    if (b < 64) {
        float t1 = sred[b][0][0] + sred[b][1][0] + sred[b][2][0] + sred[b][3][0];
        float t2 = sred[b][0][1] + sred[b][1][1] + sred[b][2][1] + sred[b][3][1];
        float mu  = t1 * (1.0f / 256.0f);
        float var = t2 * (1.0f / 256.0f) - mu * mu;
        float rs  = rsqrtf(var + EPSF);
        float aa  = p.ga[b] * rs;
        s_ac[0][b] = aa;
        s_ac[1][b] = p.ea[b] - aa * mu;
    }
    __syncthreads();

    float acc = p.ba[0];
    #pragma unroll
    for (int j = 0; j < 64; j++)
        acc += (s_ac[0][j] * v[j] + s_ac[1][j]) * p.Wa[j];
    p.out[b] = tanhf(acc) * p.Wo[0] + p.bo[0];
}

extern "C" void kernel_launch(void* const* d_in, const int* in_sizes, int n_in,
                              void* d_out, int out_size, void* d_ws, size_t ws_size,
                              hipStream_t stream) {
    Params p;
    p.x    = (const float*)d_in[0];
    p.cols0 = (const int*)d_in[2];
    p.w0   = (const float*)d_in[3];
    p.b0   = (const float*)d_in[4];
    p.cols1 = (const int*)d_in[6];
    p.w1   = (const float*)d_in[7];
    p.b1   = (const float*)d_in[8];
    p.w2   = (const float*)d_in[11];
    p.b2   = (const float*)d_in[12];
    p.gg   = (const float*)d_in[13];
    p.eg   = (const float*)d_in[14];
    p.g1   = (const float*)d_in[15];
    p.e1   = (const float*)d_in[16];
    p.g2   = (const float*)d_in[17];
    p.e2   = (const float*)d_in[18];
    p.Wd1  = (const float*)d_in[19];
    p.bd1  = (const float*)d_in[20];
    p.gd1  = (const float*)d_in[21];
    p.ed1  = (const float*)d_in[22];
    p.Wd2  = (const float*)d_in[23];
    p.bd2  = (const float*)d_in[24];
    p.gd2  = (const float*)d_in[25];
    p.ed2  = (const float*)d_in[26];
    p.Wd3  = (const float*)d_in[27];
    p.bd3  = (const float*)d_in[28];
    p.gd3  = (const float*)d_in[29];
    p.ed3  = (const float*)d_in[30];
    p.gf   = (const float*)d_in[31];
    p.ef   = (const float*)d_in[32];
    p.Wf   = (const float*)d_in[33];
    p.bf   = (const float*)d_in[34];
    p.ga   = (const float*)d_in[35];
    p.ea   = (const float*)d_in[36];
    p.Wa   = (const float*)d_in[37];
    p.ba   = (const float*)d_in[38];
    p.Wo   = (const float*)d_in[39];
    p.bo   = (const float*)d_in[40];
    p.out  = (float*)d_out;

    float* W = (float*)d_ws;
    p.gene_n = W;                         // 3000*256
    p.drug_n = p.gene_n + 3000 * NB;      // 2048*256
    p.h1n    = p.drug_n + 2048 * NB;      // 9000*256 (feature-major)
    p.h2n    = p.h1n    + 9000 * NB;      // 2400*256
    p.fbt    = p.h2n    + 2400 * NB;      // 256*56  (batch-major concat)
    p.d1n    = p.fbt    + NB * 56;        // 128*256
    p.d2n    = p.d1n    + 128 * NB;       // 64*256

    k_inbn<<<158, 256, 0, stream>>>(p);                 // S0
    k_s1  <<<1500 + 64, 256, 0, stream>>>(p);           // splin0 || dense1
    k_s2  <<<400 + 8, 256, 0, stream>>>(p);             // splin1 || dense2
    k_s3  <<<24 + 4, 256, 0, stream>>>(p);              // splin2 || dense3
    k_tail<<<1, 256, 0, stream>>>(p);                   // densef + BN + head
}

// Round 9
// 279.139 us; speedup vs baseline: 1.2629x; 1.2629x over previous
//
#include <hip/hip_runtime.h>
#include <math.h>

#define NB 256          // batch
#define XW 5048         // input row width
#define GENE 3000
#define DRUGW 2048
#define EPSF 1e-5f

struct Params {
    const float* x;
    const int* cols0; const float* w0; const float* b0;
    const int* cols1; const float* w1; const float* b1;
    const float* w2;  const float* b2;
    const float* gg;  const float* eg;
    const float* g1;  const float* e1;
    const float* g2;  const float* e2;
    const float* Wd1; const float* bd1;
    const float* gd1; const float* ed1;
    const float* Wd2; const float* bd2;
    const float* gd2; const float* ed2;
    const float* Wd3; const float* bd3;
    const float* gd3; const float* ed3;
    const float* gf;  const float* ef;
    const float* Wf;  const float* bf;
    const float* ga;  const float* ea;
    const float* Wa;  const float* ba;
    const float* Wo;  const float* bo;
    float* out;
    float* gene_n; float* drug_n; float* h1n; float* h2n;
    float* fbt;     // 56-feature concat, BATCH-major fbt[b*56+f] (rows 24..55 by dense3)
    float* d1n; float* d2n; float* part2;   // part2: 24*8*256 raw splin2 partials
};

// ---------------------------------------------------------------------------
// BN epilogue: thread b owns v[NR] for rows r0..r0+NR-1; store at out[k*RS+b*BS].
// ---------------------------------------------------------------------------
template<int NR>
__device__ __forceinline__ void bn_fold(float (&v)[NR], int b,
        const float* __restrict__ g, const float* __restrict__ e,
        float* __restrict__ out, int RS, int BS) {
    __shared__ float sred[NR][4][2];
    __shared__ float s_ac[2][NR];
    int lane = b & 63, wv = b >> 6;
    float s1[NR], s2[NR];
    #pragma unroll
    for (int k = 0; k < NR; k++) { s1[k] = v[k]; s2[k] = v[k] * v[k]; }
    #pragma unroll
    for (int off = 32; off >= 1; off >>= 1) {
        #pragma unroll
        for (int k = 0; k < NR; k++) {
            s1[k] += __shfl_xor(s1[k], off);
            s2[k] += __shfl_xor(s2[k], off);
        }
    }
    if (lane == 0) {
        #pragma unroll
        for (int k = 0; k < NR; k++) { sred[k][wv][0] = s1[k]; sred[k][wv][1] = s2[k]; }
    }
    __syncthreads();
    if (b < NR) {
        float t1 = sred[b][0][0] + sred[b][1][0] + sred[b][2][0] + sred[b][3][0];
        float t2 = sred[b][0][1] + sred[b][1][1] + sred[b][2][1] + sred[b][3][1];
        float mu  = t1 * (1.0f / 256.0f);
        float var = t2 * (1.0f / 256.0f) - mu * mu;
        float rs  = rsqrtf(var + EPSF);
        float aa  = g[b] * rs;
        s_ac[0][b] = aa;
        s_ac[1][b] = e[b] - aa * mu;
    }
    __syncthreads();
    #pragma unroll
    for (int k = 0; k < NR; k++)
        out[k * RS + b * BS] = s_ac[0][k] * v[k] + s_ac[1][k];
}

// ---------------------------------------------------------------------------
// K0: input BN. 32-col tiles, coalesced read, LDS transpose, feature-major out.
// ---------------------------------------------------------------------------
__global__ __launch_bounds__(256, 4) void k_inbn(Params p) {
    __shared__ float tile[32 * 257];
    __shared__ float red1[8][33], red2[8][33];
    __shared__ float s_a[32], s_c[32];
    int t = threadIdx.x;
    int tx = t & 31, ty = t >> 5;
    int c0 = blockIdx.x * 32;
    int c = c0 + tx;
    bool valid = c < XW;
    float s1 = 0.f, s2 = 0.f;
    #pragma unroll 8
    for (int i = 0; i < 32; i++) {
        int r = ty * 32 + i;
        float v = valid ? p.x[(size_t)r * XW + c] : 0.f;
        tile[tx * 257 + r] = v;
        s1 += v; s2 += v * v;
    }
    red1[ty][tx] = s1; red2[ty][tx] = s2;
    __syncthreads();
    if (t < 32) {
        float t1 = 0.f, t2 = 0.f;
        #pragma unroll
        for (int k = 0; k < 8; k++) { t1 += red1[k][t]; t2 += red2[k][t]; }
        float mu  = t1 * (1.0f / 256.0f);
        float var = t2 * (1.0f / 256.0f) - mu * mu;
        float rs  = rsqrtf(var + EPSF);
        int col = c0 + t;
        float gv = 0.f, ev = 0.f;
        if (col < GENE)      { gv = p.gg[col];         ev = p.eg[col]; }
        else if (col < XW)   { gv = p.gd1[col - GENE]; ev = p.ed1[col - GENE]; }
        float aa = gv * rs;
        s_a[t] = aa; s_c[t] = ev - aa * mu;
    }
    __syncthreads();
    #pragma unroll 4
    for (int cc = 0; cc < 32; cc++) {
        int col = c0 + cc;
        if (col >= XW) break;
        float w = s_a[cc] * tile[cc * 257 + t] + s_c[cc];
        if (col < GENE) p.gene_n[(size_t)col * NB + t] = w;
        else            p.drug_n[(size_t)(col - GENE) * NB + t] = w;
    }
}

// --------- dense1 helpers: 16-wide load / dual-output FMA ------------------
__device__ __forceinline__ void ld16(float (&v)[16], const float* __restrict__ dn,
                                     int c0, int b) {
    #pragma unroll
    for (int u = 0; u < 16; u++) v[u] = dn[(size_t)(c0 + u) * NB + b];
}
__device__ __forceinline__ void fma16(const float (&v)[16],
        const float* __restrict__ w0r, const float* __restrict__ w1r, int c0,
        float (&a0)[4], float (&a1)[4]) {
    #pragma unroll
    for (int u = 0; u < 16; u++) {
        a0[u & 3] += v[u] * w0r[c0 + u];
        a1[u & 3] += v[u] * w1r[c0 + u];
    }
}

// ---------------------------------------------------------------------------
// K1: splin0 (1500 tasks; 3 rounds of 10 gathers, spill-free) ||
//     dense1 (64 tasks x 2 outputs; 4-deep pipelined 16-wide rounds)
// ---------------------------------------------------------------------------
__global__ __launch_bounds__(256, 4) void k_s1(Params p) {
    int task = blockIdx.x, b = threadIdx.x;
    if (task < 1500) {
        int t = task;
        int base = t * 180;
        float acc[6] = {0.f, 0.f, 0.f, 0.f, 0.f, 0.f};
        #pragma unroll
        for (int r = 0; r < 3; r++) {
            int rb = base + r * 60;
            int cc[10];
            #pragma unroll
            for (int i = 0; i < 10; i++) cc[i] = p.cols0[rb + i * 6];
            float v[10];
            #pragma unroll
            for (int i = 0; i < 10; i++) v[i] = p.gene_n[(size_t)cc[i] * NB + b];
            #pragma unroll
            for (int i = 0; i < 10; i++)
                #pragma unroll
                for (int k = 0; k < 6; k++) acc[k] += v[i] * p.w0[rb + i * 6 + k];
        }
        float v6[6];
        #pragma unroll
        for (int k = 0; k < 6; k++) v6[k] = tanhf(acc[k] + p.b0[t * 6 + k]);
        bn_fold<6>(v6, b, p.g1 + t * 6, p.e1 + t * 6,
                   p.h1n + (size_t)t * 6 * NB, NB, 1);
    } else {
        int j0 = (task - 1500) * 2;              // 2 outputs, 2048 cols
        const float* dn  = p.drug_n;
        const float* w0r = p.Wd1 + (size_t)j0 * DRUGW;
        const float* w1r = w0r + DRUGW;
        float a0[4] = {0.f,0.f,0.f,0.f}, a1[4] = {0.f,0.f,0.f,0.f};
        float q0[16], q1[16], q2[16], q3[16];
        ld16(q0, dn, 0, b); ld16(q1, dn, 16, b); ld16(q2, dn, 32, b);
        for (int c0 = 0; c0 < 1984; c0 += 64) {
            ld16(q3, dn, c0 + 48, b);
            fma16(q0, w0r, w1r, c0, a0, a1);
            ld16(q0, dn, c0 + 64, b);
            fma16(q1, w0r, w1r, c0 + 16, a0, a1);
            ld16(q1, dn, c0 + 80, b);
            fma16(q2, w0r, w1r, c0 + 32, a0, a1);
            ld16(q2, dn, c0 + 96, b);
            fma16(q3, w0r, w1r, c0 + 48, a0, a1);
        }
        ld16(q3, dn, 2032, b);
        fma16(q0, w0r, w1r, 1984, a0, a1);
        fma16(q1, w0r, w1r, 2000, a0, a1);
        fma16(q2, w0r, w1r, 2016, a0, a1);
        fma16(q3, w0r, w1r, 2032, a0, a1);
        float v2[2];
        v2[0] = tanhf((a0[0] + a0[1]) + (a0[2] + a0[3]) + p.bd1[j0]);
        v2[1] = tanhf((a1[0] + a1[1]) + (a1[2] + a1[3]) + p.bd1[j0 + 1]);
        bn_fold<2>(v2, b, p.gd2 + j0, p.ed2 + j0,
                   p.d1n + (size_t)j0 * NB, NB, 1);
    }
}

// ---------------------------------------------------------------------------
// K2: splin1 (400 tasks) || dense2 (8 tasks x 8 outputs, 128 cols)
// ---------------------------------------------------------------------------
__global__ __launch_bounds__(256, 4) void k_s2(Params p) {
    int task = blockIdx.x, b = threadIdx.x;
    if (task < 400) {
        int o = task;
        float acc[6] = {0.f, 0.f, 0.f, 0.f, 0.f, 0.f};
        #pragma unroll
        for (int pi = 0; pi < 5; pi++) {
            int qb = (o * 5 + pi) * 36;
            int cbase = p.cols1[qb];
            float v[6];
            #pragma unroll
            for (int j = 0; j < 6; j++)
                v[j] = p.h1n[(size_t)(cbase + j) * NB + b];
            #pragma unroll
            for (int j = 0; j < 6; j++)
                #pragma unroll
                for (int i = 0; i < 6; i++)
                    acc[i] += v[j] * p.w1[qb + i * 6 + j];
        }
        float v6[6];
        #pragma unroll
        for (int i = 0; i < 6; i++) v6[i] = tanhf(acc[i] + p.b1[o * 6 + i]);
        bn_fold<6>(v6, b, p.g2 + o * 6, p.e2 + o * 6,
                   p.h2n + (size_t)o * 6 * NB, NB, 1);
    } else {
        int j0 = (task - 400) * 8;               // dense2: 128 -> 64
        float acc[8] = {0.f,0.f,0.f,0.f,0.f,0.f,0.f,0.f};
        for (int c0 = 0; c0 < 128; c0 += 16) {
            float v[16];
            #pragma unroll
            for (int u = 0; u < 16; u++)
                v[u] = p.d1n[(size_t)(c0 + u) * NB + b];
            #pragma unroll
            for (int u = 0; u < 16; u++)
                #pragma unroll
                for (int jj = 0; jj < 8; jj++)
                    acc[jj] += v[u] * p.Wd2[(size_t)(j0 + jj) * 128 + c0 + u];
        }
        float v8[8];
        #pragma unroll
        for (int jj = 0; jj < 8; jj++) v8[jj] = tanhf(acc[jj] + p.bd2[j0 + jj]);
        bn_fold<8>(v8, b, p.gd3 + j0, p.ed3 + j0,
                   p.d2n + (size_t)j0 * NB, NB, 1);
    }
}

// ---------------------------------------------------------------------------
// K3: splin2_part (192 tasks: kf x 8 chunks of 50 terms, raw partials) ||
//     dense3 (4 tasks x 8, 64 cols -> fbt rows 24..55 batch-major)
// ---------------------------------------------------------------------------
__global__ __launch_bounds__(256, 4) void k_s3(Params p) {
    int task = blockIdx.x, b = threadIdx.x;
    if (task < 192) {
        int kf = task >> 3, ch = task & 7;
        int t0 = ch * 50;
        float acc[6] = {0.f, 0.f, 0.f, 0.f, 0.f, 0.f};
        for (int r = 0; r < 10; r++) {           // 10 rounds of 5 terms (30 loads)
            int tb = t0 + r * 5;
            float v[30];
            #pragma unroll
            for (int u = 0; u < 5; u++)
                #pragma unroll
                for (int j = 0; j < 6; j++)
                    v[u * 6 + j] = p.h2n[(size_t)((tb + u) * 6 + j) * NB + b];
            #pragma unroll
            for (int u = 0; u < 5; u++) {
                const float* wt = p.w2 + (tb + u) * 144 + kf * 6;
                #pragma unroll
                for (int j = 0; j < 6; j++)
                    acc[j] += v[u * 6 + j] * wt[j];
            }
        }
        float s = ((acc[0] + acc[1]) + (acc[2] + acc[3])) + (acc[4] + acc[5]);
        p.part2[(size_t)task * NB + b] = s;      // raw partial
    } else {
        int j0 = (task - 192) * 8;               // dense3: 64 -> 32
        float acc[8] = {0.f,0.f,0.f,0.f,0.f,0.f,0.f,0.f};
        for (int c0 = 0; c0 < 64; c0 += 16) {
            float v[16];
            #pragma unroll
            for (int u = 0; u < 16; u++)
                v[u] = p.d2n[(size_t)(c0 + u) * NB + b];
            #pragma unroll
            for (int u = 0; u < 16; u++)
                #pragma unroll
                for (int jj = 0; jj < 8; jj++)
                    acc[jj] += v[u] * p.Wd3[(size_t)(j0 + jj) * 64 + c0 + u];
        }
        float v8[8];
        #pragma unroll
        for (int jj = 0; jj < 8; jj++) v8[jj] = tanhf(acc[jj] + p.bd3[j0 + jj]);
        bn_fold<8>(v8, b, p.gf + 24 + j0, p.ef + 24 + j0,
                   p.fbt + 24 + j0, 1, 56);
    }
}

// ---------------------------------------------------------------------------
// K4 (1 block): splin2 finalize (+BN via gf/ef) -> row[0..23];
// row[24..55] from fbt; densef + BN(ga,ea) + head.
// ---------------------------------------------------------------------------
__global__ __launch_bounds__(256, 2) void k_tail(Params p) {
    __shared__ float sred[64][4][2];
    __shared__ float s_ac[2][64];
    int b = threadIdx.x;
    int lane = b & 63, wv = b >> 6;

    // splin2 finalize: 24 sums of 8 partials
    float v24[24];
    #pragma unroll
    for (int kf = 0; kf < 24; kf++) {
        float s = p.b2[kf];
        #pragma unroll
        for (int ch = 0; ch < 8; ch++)
            s += p.part2[(size_t)(kf * 8 + ch) * NB + b];
        v24[kf] = tanhf(s);
    }
    // BN over batch for rows 0..23
    #pragma unroll
    for (int k = 0; k < 24; k++) {
        float s1 = v24[k], s2 = v24[k] * v24[k];
        #pragma unroll
        for (int off = 32; off >= 1; off >>= 1) {
            s1 += __shfl_xor(s1, off);
            s2 += __shfl_xor(s2, off);
        }
        if (lane == 0) { sred[k][wv][0] = s1; sred[k][wv][1] = s2; }
    }
    __syncthreads();
    if (b < 24) {
        float t1 = sred[b][0][0] + sred[b][1][0] + sred[b][2][0] + sred[b][3][0];
        float t2 = sred[b][0][1] + sred[b][1][1] + sred[b][2][1] + sred[b][3][1];
        float mu  = t1 * (1.0f / 256.0f);
        float var = t2 * (1.0f / 256.0f) - mu * mu;
        float rs  = rsqrtf(var + EPSF);
        float aa  = p.gf[b] * rs;
        s_ac[0][b] = aa;
        s_ac[1][b] = p.ef[b] - aa * mu;
    }
    __syncthreads();

    float row[56];
    #pragma unroll
    for (int k = 0; k < 24; k++)
        row[k] = s_ac[0][k] * v24[k] + s_ac[1][k];
    const float4* rp = (const float4*)(p.fbt + (size_t)b * 56 + 24);
    #pragma unroll
    for (int i = 0; i < 8; i++) {
        float4 q = rp[i];
        row[24 + i * 4 + 0] = q.x; row[24 + i * 4 + 1] = q.y;
        row[24 + i * 4 + 2] = q.z; row[24 + i * 4 + 3] = q.w;
    }
    __syncthreads();   // done reading s_ac before densef BN reuses it

    // densef: 64 outputs x 56 cols
    float v[64];
    #pragma unroll 4
    for (int j = 0; j < 64; j++) {
        float acc = p.bf[j];
        const float4* wr = (const float4*)(p.Wf + j * 56);
        #pragma unroll
        for (int i = 0; i < 14; i++) {
            float4 q = wr[i];
            acc += row[i*4+0]*q.x + row[i*4+1]*q.y + row[i*4+2]*q.z + row[i*4+3]*q.w;
        }
        v[j] = tanhf(acc);
    }

    #pragma unroll
    for (int k = 0; k < 64; k++) {
        float s1 = v[k], s2 = v[k] * v[k];
        #pragma unroll
        for (int off = 32; off >= 1; off >>= 1) {
            s1 += __shfl_xor(s1, off);
            s2 += __shfl_xor(s2, off);
        }
        if (lane == 0) { sred[k][wv][0] = s1; sred[k][wv][1] = s2; }
    }
    __syncthreads();
    if (b < 64) {
        float t1 = sred[b][0][0] + sred[b][1][0] + sred[b][2][0] + sred[b][3][0];
        float t2 = sred[b][0][1] + sred[b][1][1] + sred[b][2][1] + sred[b][3][1];
        float mu  = t1 * (1.0f / 256.0f);
        float var = t2 * (1.0f / 256.0f) - mu * mu;
        float rs  = rsqrtf(var + EPSF);
        float aa  = p.ga[b] * rs;
        s_ac[0][b] = aa;
        s_ac[1][b] = p.ea[b] - aa * mu;
    }
    __syncthreads();

    float acc = p.ba[0];
    #pragma unroll
    for (int j = 0; j < 64; j++)
        acc += (s_ac[0][j] * v[j] + s_ac[1][j]) * p.Wa[j];
    p.out[b] = tanhf(acc) * p.Wo[0] + p.bo[0];
}

extern "C" void kernel_launch(void* const* d_in, const int* in_sizes, int n_in,
                              void* d_out, int out_size, void* d_ws, size_t ws_size,
                              hipStream_t stream) {
    Params p;
    p.x    = (const float*)d_in[0];
    p.cols0 = (const int*)d_in[2];
    p.w0   = (const float*)d_in[3];
    p.b0   = (const float*)d_in[4];
    p.cols1 = (const int*)d_in[6];
    p.w1   = (const float*)d_in[7];
    p.b1   = (const float*)d_in[8];
    p.w2   = (const float*)d_in[11];
    p.b2   = (const float*)d_in[12];
    p.gg   = (const float*)d_in[13];
    p.eg   = (const float*)d_in[14];
    p.g1   = (const float*)d_in[15];
    p.e1   = (const float*)d_in[16];
    p.g2   = (const float*)d_in[17];
    p.e2   = (const float*)d_in[18];
    p.Wd1  = (const float*)d_in[19];
    p.bd1  = (const float*)d_in[20];
    p.gd1  = (const float*)d_in[21];
    p.ed1  = (const float*)d_in[22];
    p.Wd2  = (const float*)d_in[23];
    p.bd2  = (const float*)d_in[24];
    p.gd2  = (const float*)d_in[25];
    p.ed2  = (const float*)d_in[26];
    p.Wd3  = (const float*)d_in[27];
    p.bd3  = (const float*)d_in[28];
    p.gd3  = (const float*)d_in[29];
    p.ed3  = (const float*)d_in[30];
    p.gf   = (const float*)d_in[31];
    p.ef   = (const float*)d_in[32];
    p.Wf   = (const float*)d_in[33];
    p.bf   = (const float*)d_in[34];
    p.ga   = (const float*)d_in[35];
    p.ea   = (const float*)d_in[36];
    p.Wa   = (const float*)d_in[37];
    p.ba   = (const float*)d_in[38];
    p.Wo   = (const float*)d_in[39];
    p.bo   = (const float*)d_in[40];
    p.out  = (float*)d_out;

    float* W = (float*)d_ws;
    p.gene_n = W;                         // 3000*256
    p.drug_n = p.gene_n + 3000 * NB;      // 2048*256
    p.h1n    = p.drug_n + 2048 * NB;      // 9000*256 (feature-major)
    p.h2n    = p.h1n    + 9000 * NB;      // 2400*256
    p.fbt    = p.h2n    + 2400 * NB;      // 256*56 (batch-major; rows 24..55 used)
    p.d1n    = p.fbt    + NB * 56;        // 128*256
    p.d2n    = p.d1n    + 128 * NB;       // 64*256
    p.part2  = p.d2n    + 64 * NB;        // 192*256 raw splin2 partials

    k_inbn<<<158, 256, 0, stream>>>(p);                 // S0
    k_s1  <<<1500 + 64, 256, 0, stream>>>(p);           // splin0 || dense1
    k_s2  <<<400 + 8, 256, 0, stream>>>(p);             // splin1 || dense2
    k_s3  <<<192 + 4, 256, 0, stream>>>(p);             // splin2_part || dense3
    k_tail<<<1, 256, 0, stream>>>(p);                   // splin2_fin + densef + head
}